// Round 9
// baseline (2627.606 us; speedup 1.0000x reference)
//
#include <hip/hip_runtime.h>
#include <hip/hip_fp16.h>

constexpr int LEN = 5265;
constexpr long NTOK = 8L * LEN;   // 42120

typedef float f32x4 __attribute__((ext_vector_type(4)));
typedef unsigned int u32x4 __attribute__((ext_vector_type(4)));

static __device__ __forceinline__ unsigned short f2bf(float f) {
    unsigned u = __float_as_uint(f);
    unsigned r = (u + 0x7FFFu + ((u >> 16) & 1u)) >> 16;
    return (unsigned short)r;
}

#if __has_builtin(__builtin_amdgcn_global_load_lds)
#define HAS_GLL 1
static __device__ __forceinline__ void gll16(const void* g, void* l) {
    __builtin_amdgcn_global_load_lds(
        (const __attribute__((address_space(1))) void*)g,
        (__attribute__((address_space(3))) void*)l, 16, 0, 0);
}
#else
#define HAS_GLL 0
#endif

// ---------------------------------------------------------------- pack
__global__ __launch_bounds__(256) void pack_kernel(
    const float* __restrict__ s0, const float* __restrict__ s1,
    const float* __restrict__ s2, const float* __restrict__ s3,
    const float* __restrict__ p0, const float* __restrict__ p1,
    const float* __restrict__ p2, const float* __restrict__ p3,
    const float* __restrict__ lev,
    float* __restrict__ x, float* __restrict__ pos,
    unsigned short* __restrict__ xbf, unsigned short* __restrict__ qbf)
{
    long t = (long)blockIdx.x * 256 + threadIdx.x;
    if (t >= NTOK * 256) return;
    int c = (int)(t & 255);
    long r = t >> 8;
    int q = (int)(r % LEN);
    int B = (int)(r / LEN);
    int lvl, base, n;
    const float *sp, *pp;
    if (q < 4608)      { lvl = 0; base = 0;    n = 4608; sp = s0; pp = p0; }
    else if (q < 5184) { lvl = 1; base = 4608; n = 576;  sp = s1; pp = p1; }
    else if (q < 5256) { lvl = 2; base = 5184; n = 72;   sp = s2; pp = p2; }
    else               { lvl = 3; base = 5256; n = 9;    sp = s3; pp = p3; }
    int s = q - base;
    long si = ((long)B * 256 + c) * n + s;
    float xv = sp[si];
    float pv = pp[si] + lev[lvl * 256 + c];
    x[t] = xv;
    pos[t] = pv;
    xbf[t] = f2bf(xv);
    qbf[t] = f2bf(xv + pv);
}

// ---------------------------------------------------------------- ref points
__global__ __launch_bounds__(64) void ref_kernel(float* __restrict__ refb)
{
    int q = blockIdx.x * 64 + threadIdx.x;
    if (q >= LEN) return;
    int base, D_, H_, W_;
    if (q < 4608)      { base = 0;    D_ = 8; H_ = 24; W_ = 24; }
    else if (q < 5184) { base = 4608; D_ = 4; H_ = 12; W_ = 12; }
    else if (q < 5256) { base = 5184; D_ = 2; H_ = 6;  W_ = 6;  }
    else               { base = 5256; D_ = 1; H_ = 3;  W_ = 3;  }
    int s = q - base;
    int hw = H_ * W_;
    int z = s / hw; int rem = s - z * hw;
    int y = rem / W_; int xx = rem - y * W_;
    refb[q * 3 + 0] = (xx + 0.5f) / (float)W_;
    refb[q * 3 + 1] = (y + 0.5f) / (float)H_;
    refb[q * 3 + 2] = (z + 0.5f) / (float)D_;
}

// ---------------------------------------------------------------- weight transpose+cvt
// src (L,K,N) f32 -> dst (L as dstLS, N, K) bf16
__global__ __launch_bounds__(256) void wtrans_kernel(
    const float* __restrict__ src, unsigned short* __restrict__ dst,
    int K, int N, long dstLS)
{
    __shared__ float t[32][33];
    const int k0 = blockIdx.x * 32, n0 = blockIdx.y * 32;
    src += (long)blockIdx.z * K * N;
    dst += (long)blockIdx.z * dstLS;
    const int tx = threadIdx.x, ty = threadIdx.y;
    for (int i = ty; i < 32; i += 8)
        t[i][tx] = src[(long)(k0 + i) * N + n0 + tx];
    __syncthreads();
    for (int i = ty; i < 32; i += 8)
        dst[(long)(n0 + i) * K + k0 + tx] = f2bf(t[tx][i]);
}

// ---------------------------------------------------------------- MFMA GEMM
// C[M,N] = A[M,K](bf16) @ Wt[N,K](bf16)^T + bias; 128x128 tile, BK=32,
// 256 thr = 4 waves (2x2), each wave 64x64 = 4x4 frags of 16x16x32.
// Staging: global_load_lds w=16, linear LDS dest, pre-swizzled global source.
static __device__ __forceinline__ int swz(int m) { return (m ^ (m >> 2)) & 3; }

template<bool OUTBF, bool RELU>
__global__ __launch_bounds__(256) void mfma_gemm(
    const unsigned short* __restrict__ A, const unsigned short* __restrict__ Wt,
    const float* __restrict__ bias, const float* __restrict__ bias2, int nb0,
    void* __restrict__ Cv, int M, int K, int N)
{
    __shared__ u32x4 a_l[512];  // slot = row*4 + s; slot s holds chunk s^swz(row)
    __shared__ u32x4 b_l[512];
    const int tid = threadIdx.x;
    const int row0 = blockIdx.x * 128;
    const int col0 = blockIdx.y * 128;
    const int wave = tid >> 6, lane = tid & 63;
    const int wr = wave >> 1, wc = wave & 1;
    const int l15 = lane & 15, l4 = lane >> 4;

    f32x4 acc[4][4];
#pragma unroll
    for (int i = 0; i < 4; ++i)
#pragma unroll
        for (int j = 0; j < 4; ++j) acc[i][j] = (f32x4){0.f, 0.f, 0.f, 0.f};

    const int sm0 = tid >> 2, sk = tid & 3;
    const int swk = (sk ^ swz(sm0)) * 8;      // swz(sm0+64)==swz(sm0)
    const int arA0 = min(row0 + sm0, M - 1);  // clamped rows only affect C rows >=M
    const int arA1 = min(row0 + sm0 + 64, M - 1);
    const unsigned short* gA0 = A  + (long)arA0 * K + swk;
    const unsigned short* gA1 = A  + (long)arA1 * K + swk;
    const unsigned short* gB0 = Wt + (long)(col0 + sm0) * K + swk;
    const unsigned short* gB1 = Wt + (long)(col0 + sm0 + 64) * K + swk;

    for (int k0 = 0; k0 < K; k0 += 32) {
        __syncthreads();                       // all waves done reading prev tile
#if HAS_GLL
        gll16(gA0 + k0, &a_l[wave * 64]);
        gll16(gA1 + k0, &a_l[256 + wave * 64]);
        gll16(gB0 + k0, &b_l[wave * 64]);
        gll16(gB1 + k0, &b_l[256 + wave * 64]);
#else
        a_l[tid]       = *(const u32x4*)(gA0 + k0);
        a_l[256 + tid] = *(const u32x4*)(gA1 + k0);
        b_l[tid]       = *(const u32x4*)(gB0 + k0);
        b_l[256 + tid] = *(const u32x4*)(gB1 + k0);
#endif
        __syncthreads();                       // drains vmcnt -> LDS filled
        u32x4 af[4], bfr[4];
#pragma unroll
        for (int i = 0; i < 4; ++i) {
            const int m = wr * 64 + i * 16 + l15;
            af[i] = a_l[m * 4 + (l4 ^ swz(m))];
            const int n = wc * 64 + i * 16 + l15;
            bfr[i] = b_l[n * 4 + (l4 ^ swz(n))];
        }
#pragma unroll
        for (int i = 0; i < 4; ++i)
#pragma unroll
            for (int j = 0; j < 4; ++j)
                asm volatile("v_mfma_f32_16x16x32_bf16 %0, %1, %2, %0"
                             : "+v"(acc[i][j]) : "v"(af[i]), "v"(bfr[j]));
    }

    float* Cf = (float*)Cv;
    unsigned short* Cb = (unsigned short*)Cv;
    const int cb = col0 + wc * 64;
    float bj[4];
#pragma unroll
    for (int j = 0; j < 4; ++j) {
        const int col = cb + j * 16 + l15;
        bj[j] = (col < nb0) ? bias[col] : bias2[col - nb0];
    }
#pragma unroll
    for (int i = 0; i < 4; ++i) {
        const int rb = row0 + wr * 64 + i * 16 + l4 * 4;
#pragma unroll
        for (int r = 0; r < 4; ++r) {
            const int row = rb + r;
            if (row < M) {
#pragma unroll
                for (int j = 0; j < 4; ++j) {
                    const int col = cb + j * 16 + l15;
                    float v = acc[i][j][r] + bj[j];
                    if (RELU) v = fmaxf(v, 0.f);
                    if (OUTBF) Cb[(long)row * N + col] = f2bf(v);
                    else       Cf[(long)row * N + col] = v;
                }
            }
        }
    }
}

// ---------------------------------------------------------------- MSDA sampling
// 64 groups/block (8 tokens). Phase1: shuffle softmax (coalesced logit loads),
// 8 corners -> (u16 tokidx | f16 w) in LDS. Phase2: 4 lanes x 8 f32 channels
// per group; no unpack (value is f32), 32-bit voffset addressing.
__global__ __launch_bounds__(256) void msda_sample_kernel(
    const float* __restrict__ value,   // f32 (tok,256)
    const float* __restrict__ obuf,    // f32 (tok,512): off[0:384], logits[384:512]
    const float* __restrict__ refb,    // (LEN,3)
    unsigned short* __restrict__ outb) // bf16 (tok,256)
{
    __shared__ unsigned s_wi[64 * 137];        // 35072 B; group stride 137
    const int tid = threadIdx.x;
    const long gid0 = (long)blockIdx.x * 64;

#pragma unroll
    for (int jj = 0; jj < 4; ++jj) {
        const int j = jj * 256 + tid;          // 0..1023 = 64 groups x 16 pts
        const int g = j >> 4, pt = j & 15;
        const long gg = gid0 + g;
        const int h = (int)(gg & 7);
        const long tok = gg >> 3;
        const int q = (int)(tok % LEN);
        const int b = (int)(tok / LEN);

        // wave-parallel softmax over the 16 pt-lanes of this group
        const float lgv = obuf[tok * 512 + 384 + h * 16 + pt];
        float m = lgv;
#pragma unroll
        for (int o = 1; o < 16; o <<= 1) m = fmaxf(m, __shfl_xor(m, o));
        const float e = __expf(lgv - m);
        float den = e;
#pragma unroll
        for (int o = 1; o < 16; o <<= 1) den += __shfl_xor(den, o);
        const float aw = e / den;

        const int lvl = pt >> 2;
        int D_, H_, W_, base;
        if (lvl == 0)      { D_ = 8; H_ = 24; W_ = 24; base = 0; }
        else if (lvl == 1) { D_ = 4; H_ = 12; W_ = 12; base = 4608; }
        else if (lvl == 2) { D_ = 2; H_ = 6;  W_ = 6;  base = 5184; }
        else               { D_ = 1; H_ = 3;  W_ = 3;  base = 5256; }
        const float fW = (float)W_, fH = (float)H_, fD = (float)D_;

        const float* op = &obuf[tok * 512 + h * 48 + pt * 3];
        const float X = (refb[q * 3 + 0] + op[0] / fW) * fW - 0.5f;
        const float Y = (refb[q * 3 + 1] + op[1] / fH) * fH - 0.5f;
        const float Z = (refb[q * 3 + 2] + op[2] / fD) * fD - 0.5f;
        const float x0f = floorf(X), y0f = floorf(Y), z0f = floorf(Z);
        const float fx = X - x0f, fy = Y - y0f, fz = Z - z0f;
        const int x0 = (int)x0f, y0 = (int)y0f, z0 = (int)z0f;
#pragma unroll
        for (int c = 0; c < 8; ++c) {
            const int dx = c & 1, dy = (c >> 1) & 1, dz = c >> 2;
            const int xi = x0 + dx, yi = y0 + dy, zi = z0 + dz;
            float w = (dx ? fx : 1.f - fx) * (dy ? fy : 1.f - fy) * (dz ? fz : 1.f - fz);
            const bool valid = (xi >= 0) && (xi < W_) && (yi >= 0) && (yi < H_) &&
                               (zi >= 0) && (zi < D_);
            const int xc = min(max(xi, 0), W_ - 1);
            const int yc = min(max(yi, 0), H_ - 1);
            const int zc = min(max(zi, 0), D_ - 1);
            const int n = (zc * H_ + yc) * W_ + xc;
            const unsigned ti = (unsigned)(b * LEN + base + n);  // < 42120
            const unsigned short hw =
                __half_as_ushort(__float2half_rn(valid ? w * aw : 0.f));
            s_wi[g * 137 + c * 17 + pt] = (ti << 16) | (unsigned)hw;
        }
    }
    __syncthreads();

    const int g = tid >> 2, d8 = tid & 3;      // 64 groups x 4 lanes
    const long gg = gid0 + g;
    const int h = (int)(gg & 7);
    const float* vbase = value + h * 32 + d8 * 8;
    const unsigned* sp = &s_wi[g * 137];
    float a[8];
#pragma unroll
    for (int k = 0; k < 8; ++k) a[k] = 0.f;
#pragma unroll 16
    for (int i = 0; i < 128; ++i) {
        const unsigned word = sp[i + (i >> 4)];              // c*17+pt
        const float w = __half2float(__ushort_as_half((unsigned short)word));
        const float* vp = vbase + ((long)(word >> 16) << 8); // tok*256 floats
        const f32x4 v0 = *(const f32x4*)vp;
        const f32x4 v1 = *(const f32x4*)(vp + 4);
#pragma unroll
        for (int k = 0; k < 4; ++k) a[k] += w * v0[k];
#pragma unroll
        for (int k = 0; k < 4; ++k) a[4 + k] += w * v1[k];
    }
    u32x4 o;
#pragma unroll
    for (int k = 0; k < 4; ++k)
        o[k] = (unsigned)f2bf(a[2 * k]) | ((unsigned)f2bf(a[2 * k + 1]) << 16);
    *(u32x4*)&outb[gg * 32 + d8 * 8] = o;
}

// ---------------------------------------------------------------- residual + LN
template<bool NEEDQ>
__global__ __launch_bounds__(256) void resid_ln_kernel(
    float* __restrict__ x, const float* __restrict__ r, const float* __restrict__ pos,
    const float* __restrict__ g, const float* __restrict__ be,
    unsigned short* __restrict__ xbf, unsigned short* __restrict__ qbf)
{
    const long tok = (long)blockIdx.x * 4 + (threadIdx.x >> 6);
    const int lane = threadIdx.x & 63;
    if (tok >= NTOK) return;
    const float4 xv = *(const float4*)&x[tok * 256 + lane * 4];
    const float4 rv = *(const float4*)&r[tok * 256 + lane * 4];
    float s0 = xv.x + rv.x, s1 = xv.y + rv.y, s2 = xv.z + rv.z, s3 = xv.w + rv.w;
    float sum = s0 + s1 + s2 + s3;
#pragma unroll
    for (int o = 32; o > 0; o >>= 1) sum += __shfl_xor(sum, o);
    const float mean = sum * (1.f / 256.f);
    const float d0 = s0 - mean, d1 = s1 - mean, d2 = s2 - mean, d3 = s3 - mean;
    float vs = d0 * d0 + d1 * d1 + d2 * d2 + d3 * d3;
#pragma unroll
    for (int o = 32; o > 0; o >>= 1) vs += __shfl_xor(vs, o);
    const float rstd = rsqrtf(vs * (1.f / 256.f) + 1e-5f);
    float4 o4;
    o4.x = d0 * rstd * g[lane * 4 + 0] + be[lane * 4 + 0];
    o4.y = d1 * rstd * g[lane * 4 + 1] + be[lane * 4 + 1];
    o4.z = d2 * rstd * g[lane * 4 + 2] + be[lane * 4 + 2];
    o4.w = d3 * rstd * g[lane * 4 + 3] + be[lane * 4 + 3];
    *(float4*)&x[tok * 256 + lane * 4] = o4;
    ushort4 xb;
    xb.x = f2bf(o4.x); xb.y = f2bf(o4.y); xb.z = f2bf(o4.z); xb.w = f2bf(o4.w);
    *(ushort4*)&xbf[tok * 256 + lane * 4] = xb;
    if (NEEDQ) {
        const float4 pv = *(const float4*)&pos[tok * 256 + lane * 4];
        ushort4 qb;
        qb.x = f2bf(o4.x + pv.x); qb.y = f2bf(o4.y + pv.y);
        qb.z = f2bf(o4.z + pv.z); qb.w = f2bf(o4.w + pv.w);
        *(ushort4*)&qbf[tok * 256 + lane * 4] = qb;
    }
}

// ---------------------------------------------------------------- launch
extern "C" void kernel_launch(void* const* d_in, const int* in_sizes, int n_in,
                              void* d_out, int out_size, void* d_ws, size_t ws_size,
                              hipStream_t stream)
{
    (void)n_in; (void)out_size; (void)ws_size;
    const float* src[4];
    const float* posin[4];
    const bool interleaved = (in_sizes[1] == in_sizes[0]);
    for (int i = 0; i < 4; ++i) {
        if (interleaved) { src[i] = (const float*)d_in[2 * i]; posin[i] = (const float*)d_in[2 * i + 1]; }
        else             { src[i] = (const float*)d_in[i];     posin[i] = (const float*)d_in[4 + i]; }
    }
    const float* lev    = (const float*)d_in[8];
    const float* W_off  = (const float*)d_in[9];
    const float* b_off  = (const float*)d_in[10];
    const float* W_attn = (const float*)d_in[11];
    const float* b_attn = (const float*)d_in[12];
    const float* W_val  = (const float*)d_in[13];
    const float* b_val  = (const float*)d_in[14];
    const float* W_out  = (const float*)d_in[15];
    const float* b_out  = (const float*)d_in[16];
    const float* g1     = (const float*)d_in[17];
    const float* be1    = (const float*)d_in[18];
    const float* W1     = (const float*)d_in[19];
    const float* b1     = (const float*)d_in[20];
    const float* W2     = (const float*)d_in[21];
    const float* b2     = (const float*)d_in[22];
    const float* g2     = (const float*)d_in[23];
    const float* be2    = (const float*)d_in[24];

    float* xbuf = (float*)d_out;
    char* p = (char*)d_ws;
    float* posb = (float*)p;            p += NTOK * 256 * 4;   // 43.1MB
    float* tmp  = (float*)p;                                    // f32 (tok,256)
    float* valuef = tmp;                                        // f32 value (tok,256)
                                        p += NTOK * 256 * 4;   // 43.1MB
    float* obuf = (float*)p;                                    // f32 (tok,512) off|logits
    unsigned short* hidden = (unsigned short*)obuf;             // bf16 alias (tok,1024)
                                        p += NTOK * 512 * 4;   // 86.3MB
    unsigned short* msdabf = (unsigned short*)p;  p += NTOK * 256 * 2;
    unsigned short* xbf    = (unsigned short*)p;  p += NTOK * 256 * 2;
    unsigned short* qbf    = (unsigned short*)p;  p += NTOK * 256 * 2;
    unsigned short* wt_val = (unsigned short*)p;  p += 6L * 256 * 256 * 2;
    unsigned short* wt_oa  = (unsigned short*)p;  p += 6L * 512 * 256 * 2;
    unsigned short* wt_out = (unsigned short*)p;  p += 6L * 256 * 256 * 2;
    unsigned short* wt_w1  = (unsigned short*)p;  p += 6L * 1024 * 256 * 2;
    unsigned short* wt_w2  = (unsigned short*)p;  p += 6L * 256 * 1024 * 2;
    float* refb = (float*)p;            p += LEN * 3 * 4;

    pack_kernel<<<(int)((NTOK * 256) / 256), 256, 0, stream>>>(
        src[0], src[1], src[2], src[3], posin[0], posin[1], posin[2], posin[3],
        lev, xbuf, posb, xbf, qbf);
    ref_kernel<<<(LEN + 63) / 64, 64, 0, stream>>>(refb);
    dim3 tb(32, 8);
    wtrans_kernel<<<dim3(8, 8, 6),  tb, 0, stream>>>(W_val,  wt_val, 256, 256,  65536);
    wtrans_kernel<<<dim3(8, 12, 6), tb, 0, stream>>>(W_off,  wt_oa,  256, 384,  131072);
    wtrans_kernel<<<dim3(8, 4, 6),  tb, 0, stream>>>(W_attn, wt_oa + 384 * 256, 256, 128, 131072);
    wtrans_kernel<<<dim3(8, 8, 6),  tb, 0, stream>>>(W_out,  wt_out, 256, 256,  65536);
    wtrans_kernel<<<dim3(8, 32, 6), tb, 0, stream>>>(W1,     wt_w1,  256, 1024, 262144);
    wtrans_kernel<<<dim3(32, 8, 6), tb, 0, stream>>>(W2,     wt_w2,  1024, 256, 262144);

    const int MT = (int)((NTOK + 127) / 128);  // 330
    const int BIG = 1 << 30;
    for (int l = 0; l < 6; ++l) {
        mfma_gemm<false, false><<<dim3(MT, 2), 256, 0, stream>>>(
            xbf, wt_val + (long)l * 65536, b_val + l * 256, b_val + l * 256, BIG,
            valuef, (int)NTOK, 256, 256);
        mfma_gemm<false, false><<<dim3(MT, 4), 256, 0, stream>>>(
            qbf, wt_oa + (long)l * 131072, b_off + l * 384, b_attn + l * 128, 384,
            obuf, (int)NTOK, 256, 512);
        msda_sample_kernel<<<(int)(NTOK / 8), 256, 0, stream>>>(
            valuef, obuf, refb, msdabf);
        mfma_gemm<false, false><<<dim3(MT, 2), 256, 0, stream>>>(
            msdabf, wt_out + (long)l * 65536, b_out + l * 256, b_out + l * 256, BIG,
            tmp, (int)NTOK, 256, 256);
        resid_ln_kernel<false><<<(int)((NTOK + 3) / 4), 256, 0, stream>>>(
            xbuf, tmp, posb, g1 + l * 256, be1 + l * 256, xbf, qbf);
        mfma_gemm<true, true><<<dim3(MT, 8), 256, 0, stream>>>(
            xbf, wt_w1 + (long)l * 262144, b1 + l * 1024, b1 + l * 1024, BIG,
            hidden, (int)NTOK, 256, 1024);
        mfma_gemm<false, false><<<dim3(MT, 2), 256, 0, stream>>>(
            hidden, wt_w2 + (long)l * 262144, b2 + l * 256, b2 + l * 256, BIG,
            tmp, (int)NTOK, 1024, 256);
        resid_ln_kernel<true><<<(int)((NTOK + 3) / 4), 256, 0, stream>>>(
            xbuf, tmp, posb, g2 + l * 256, be2 + l * 256, xbf, qbf);
    }
}